// Round 11
// baseline (447.885 us; speedup 1.0000x reference)
//
#include <hip/hip_runtime.h>
#include <cstdint>

typedef unsigned char u8;
typedef unsigned short u16;
typedef unsigned int u32;

#define V_N 500000
#define G_N 25000
#define F_N 256
#define GP_N 25088  // G padded to multiple of 128 for GEMM tiles

#define CONVW_BLK 4608       // weight-conversion blocks (head of grid)
#define NODE_BLK (GP_N / 4)  // 6272 node blocks (4 waves/block, wave-per-graph)
#define CAP 32               // LDS fp8 row-cache capacity (P(n>32) ~ 0.4%)

typedef __attribute__((ext_vector_type(8))) __bf16 bf16x8;
typedef __attribute__((ext_vector_type(4))) float f32x4;

__device__ __forceinline__ u16 f2bf(float f) {
  u32 u = __builtin_bit_cast(u32, f);
  u += 0x7fffu + ((u >> 16) & 1u);
  return (u16)(u >> 16);
}
__device__ __forceinline__ float bf2f(u16 s) {
  u32 u = ((u32)s) << 16;
  return __builtin_bit_cast(float, u);
}
// ---- fp8 e4m3fn encode/decode via bit tricks (verified r10) ----
__device__ __forceinline__ u32 f2e4m3(float f) {
  u32 b = __builtin_bit_cast(u32, f * 0x1p-120f);
  u32 s = (b >> 24) & 0x80u;
  u32 ax = b & 0x7fffffffu;
  u32 r = (ax + 0x7FFFFu + ((ax >> 20) & 1u)) >> 20;
  r = r > 0x7Eu ? 0x7Eu : r;
  return s | r;
}
__device__ __forceinline__ float e4m3f(u32 byte) {
  u32 bits = ((byte & 0x80u) << 24) | ((byte & 0x7fu) << 20);
  return __builtin_bit_cast(float, bits) * 0x1p120f;
}
__device__ __forceinline__ float sigm(float x) { return 1.f / (1.f + __expf(-x)); }
__device__ __forceinline__ float tanh_fast(float x) {
  return 1.f - 2.f / (__expf(2.f * x) + 1.f);
}
__device__ __forceinline__ float lrelu(float z) { return z >= 0.f ? z : 0.01f * z; }

// ---- DPP wave reductions (verified r8) ----
template <int CTRL>
__device__ __forceinline__ float dpp_add_f(float v) {
  int t = __builtin_amdgcn_update_dpp(0, __builtin_bit_cast(int, v), CTRL, 0xF, 0xF, true);
  return v + __builtin_bit_cast(float, t);
}
template <int CTRL>
__device__ __forceinline__ float dpp_max_f(float v) {
  int t = __builtin_amdgcn_update_dpp(0, __builtin_bit_cast(int, v), CTRL, 0xF, 0xF, true);
  return fmaxf(v, __builtin_bit_cast(float, t));
}
__device__ __forceinline__ float wave_sum(float v) {
  v = dpp_add_f<0xB1>(v);
  v = dpp_add_f<0x4E>(v);
  v = dpp_add_f<0x141>(v);
  v = dpp_add_f<0x140>(v);
  v += __shfl_xor(v, 16, 64);
  v += __shfl_xor(v, 32, 64);
  return v;
}
__device__ __forceinline__ float wave_max(float v) {
  v = dpp_max_f<0xB1>(v);
  v = dpp_max_f<0x4E>(v);
  v = dpp_max_f<0x141>(v);
  v = dpp_max_f<0x140>(v);
  v = fmaxf(v, __shfl_xor(v, 16, 64));
  v = fmaxf(v, __shfl_xor(v, 32, 64));
  return v;
}

__device__ __forceinline__ void load_lds16(const void* g, void* l) {
  __builtin_amdgcn_global_load_lds(
      (const __attribute__((address_space(1))) void*)g,
      (__attribute__((address_space(3))) void*)l, 16, 0, 0);
}

// ---------------- fused node pass + t=0 attention + offsets + weight conv ----------------
// Blocks [0, CONVW_BLK): weight conversion (runs FIRST, hides under node stream).
// Blocks [CONVW_BLK, +NODE_BLK): wave-per-graph node pass with LDS fp8 row cache;
// t0 weighted sum reads the cache (no vmcnt drain, no L2 re-read) when n<=CAP.
__global__ __launch_bounds__(256) void k_node_fused(const float* __restrict__ nf,
                                                    const int* __restrict__ seg,
                                                    const float* __restrict__ Wl,
                                                    const float* __restrict__ bl,
                                                    u8* __restrict__ xb,
                                                    float* __restrict__ q0, float* __restrict__ q1,
                                                    float* __restrict__ hbuf0, u16* __restrict__ x2a,
                                                    u16* __restrict__ x2b,
                                                    u16* __restrict__ sb, float* __restrict__ Ag,
                                                    int* __restrict__ off,
                                                    const float* __restrict__ Wp,
                                                    const float* __restrict__ Wih,
                                                    const float* __restrict__ Whh,
                                                    u16* __restrict__ Wpb, u16* __restrict__ W3) {
  if (blockIdx.x < CONVW_BLK) {  // ---- weight conversion (verified r3) ----
    int i = blockIdx.x * 256 + threadIdx.x;
    const int NP = 2 * F_N * F_N;  // 131072
    if (i < NP) {
      Wpb[i] = f2bf(Wp[i]);
      return;
    }
    int j = i - NP;  // < 2*1024*512
    int t = j >> 19;
    int r = j & 524287;
    int row = r >> 9;
    int k = r & 511;
    int q = row >> 6;
    int gate = (row >> 4) & 3;
    int c = q * 16 + (row & 15);
    const float* wi = Wih + t * 196608;
    const float* wh = Whh + t * 196608;
    float v;
    if (gate == 0) {
      v = (k < 256) ? wi[c * 256 + k] : wh[c * 256 + (k - 256)];
    } else if (gate == 1) {
      v = (k < 256) ? wi[(256 + c) * 256 + k] : wh[(256 + c) * 256 + (k - 256)];
    } else if (gate == 2) {
      v = (k < 256) ? wi[(512 + c) * 256 + k] : 0.f;
    } else {
      v = (k >= 256) ? wh[(512 + c) * 256 + (k - 256)] : 0.f;
    }
    W3[j] = f2bf(v);
    return;
  }

  __shared__ u8 xcache[4][CAP][F_N];  // 32 KB fp8 row cache (per-wave slice)
  int wv = threadIdx.x >> 6;
  int g = (blockIdx.x - CONVW_BLK) * 4 + wv;
  int lane = threadIdx.x & 63;
  if (g >= G_N) {  // padding cleanup
    if (g == G_N && lane == 0) off[G_N] = V_N;
    if (g >= GP_N) return;
    float4 z4 = {0.f, 0.f, 0.f, 0.f};
    uint2 z2 = {0u, 0u};
    *reinterpret_cast<float4*>(hbuf0 + (size_t)g * F_N + lane * 4) = z4;
    *reinterpret_cast<uint2*>(x2a + (size_t)g * 512 + 256 + lane * 4) = z2;
    *reinterpret_cast<uint2*>(x2b + (size_t)g * 512 + 256 + lane * 4) = z2;
    *reinterpret_cast<uint2*>(sb + (size_t)g * F_N + lane * 4) = z2;
    if (lane == 0) Ag[g] = 0.f;
    return;
  }
  // ---- segment bounds via binary search (lane&1 -> target g / g+1) ----
  int tgt = g + (lane & 1);
  int lo = 0, hi = V_N;
  while (lo < hi) {
    int mid = (lo + hi) >> 1;
    bool lt = seg[mid] < tgt;
    lo = lt ? mid + 1 : lo;
    hi = lt ? hi : mid;
  }
  int s = __shfl(lo, 0, 64);
  int e = __shfl(lo, 1, 64);
  if (lane == 0) off[g] = s;  // for k_attn
  const float4 w0 = *reinterpret_cast<const float4*>(Wl + 256 + lane * 4);
  const float4 w1 = *reinterpret_cast<const float4*>(Wl + 768 + lane * 4);
  const float4 wh = *reinterpret_cast<const float4*>(Wl + lane * 4);  // t0 h-part
  int n = e - s;
  float a0 = 0.f, a1 = 0.f, a2 = 0.f, a3 = 0.f;
  float qreg = 0.f;
  int v = s;
  for (; v + 2 <= e; v += 2) {
    const float4 xA = *reinterpret_cast<const float4*>(nf + (size_t)v * F_N + lane * 4);
    const float4 xB = *reinterpret_cast<const float4*>(nf + (size_t)(v + 1) * F_N + lane * 4);
    a0 += xA.x + xB.x; a1 += xA.y + xB.y; a2 += xA.z + xB.z; a3 += xA.w + xB.w;
    u32 pA = f2e4m3(xA.x) | (f2e4m3(xA.y) << 8) | (f2e4m3(xA.z) << 16) | (f2e4m3(xA.w) << 24);
    u32 pB = f2e4m3(xB.x) | (f2e4m3(xB.y) << 8) | (f2e4m3(xB.z) << 16) | (f2e4m3(xB.w) << 24);
    *reinterpret_cast<u32*>(xb + (size_t)v * F_N + lane * 4) = pA;
    *reinterpret_cast<u32*>(xb + (size_t)(v + 1) * F_N + lane * 4) = pB;
    int li = v - s;
    if (li < CAP) *reinterpret_cast<u32*>(&xcache[wv][li][lane * 4]) = pA;
    if (li + 1 < CAP) *reinterpret_cast<u32*>(&xcache[wv][li + 1][lane * 4]) = pB;
    float dA0 = wave_sum(xA.x * w0.x + xA.y * w0.y + xA.z * w0.z + xA.w * w0.w);
    float dA1 = wave_sum(xA.x * w1.x + xA.y * w1.y + xA.z * w1.z + xA.w * w1.w);
    float dB0 = wave_sum(xB.x * w0.x + xB.y * w0.y + xB.z * w0.z + xB.w * w0.w);
    float dB1 = wave_sum(xB.x * w1.x + xB.y * w1.y + xB.z * w1.z + xB.w * w1.w);
    if (lane == 0) {
      q0[v] = dA0; q1[v] = dA1;
      q0[v + 1] = dB0; q1[v + 1] = dB1;
    }
    if (li == lane) qreg = dA0;
    if (li + 1 == lane) qreg = dB0;
  }
  if (v < e) {
    const float4 xA = *reinterpret_cast<const float4*>(nf + (size_t)v * F_N + lane * 4);
    a0 += xA.x; a1 += xA.y; a2 += xA.z; a3 += xA.w;
    u32 pA = f2e4m3(xA.x) | (f2e4m3(xA.y) << 8) | (f2e4m3(xA.z) << 16) | (f2e4m3(xA.w) << 24);
    *reinterpret_cast<u32*>(xb + (size_t)v * F_N + lane * 4) = pA;
    int li = v - s;
    if (li < CAP) *reinterpret_cast<u32*>(&xcache[wv][li][lane * 4]) = pA;
    float dA0 = wave_sum(xA.x * w0.x + xA.y * w0.y + xA.z * w0.z + xA.w * w0.w);
    float dA1 = wave_sum(xA.x * w1.x + xA.y * w1.y + xA.z * w1.z + xA.w * w1.w);
    if (lane == 0) { q0[v] = dA0; q1[v] = dA1; }
    if (li == lane) qreg = dA0;
  }
  // h0 outputs
  float4 h4 = {a0, a1, a2, a3};
  *reinterpret_cast<float4*>(hbuf0 + (size_t)g * F_N + lane * 4) = h4;
  uint2 hs;
  hs.x = (u32)f2bf(a0) | ((u32)f2bf(a1) << 16);
  hs.y = (u32)f2bf(a2) | ((u32)f2bf(a3) << 16);
  *reinterpret_cast<uint2*>(x2a + (size_t)g * 512 + 256 + lane * 4) = hs;

  // ---- fused t=0 attention ----
  if (n == 0) {
    if (lane < 32) {
      uint4 z = {0u, 0u, 0u, 0u};
      *reinterpret_cast<uint4*>(sb + (size_t)g * F_N + lane * 8) = z;
    }
    if (lane == 0) Ag[g] = 0.f;
    return;
  }
  float p = wave_sum(fmaxf(a0, 0.f) * wh.x + fmaxf(a1, 0.f) * wh.y +
                     fmaxf(a2, 0.f) * wh.z + fmaxf(a3, 0.f) * wh.w) + bl[0];

  if (n <= CAP) {
    // ---- fast path: softmax in registers, weighted sum from LDS cache ----
    // (no vmcnt drain: nothing global is re-read)
    float z = (lane < n) ? lrelu(p + qreg) : -3.4e38f;
    float mx = wave_max(z);
    float ee = (lane < n) ? __expf(z - mx) : 0.f;
    float inv = 1.f / wave_sum(ee);
    float acc0 = 0.f, acc1 = 0.f, acc2 = 0.f, acc3 = 0.f;
    for (int i = 0; i < n; ++i) {
      float a = __shfl(ee, i, 64) * inv;
      u32 x = *reinterpret_cast<const u32*>(&xcache[wv][i][lane * 4]);
      acc0 += a * e4m3f(x & 0xffu);
      acc1 += a * e4m3f((x >> 8) & 0xffu);
      acc2 += a * e4m3f((x >> 16) & 0xffu);
      acc3 += a * e4m3f(x >> 24);
    }
    uint2 o;
    o.x = (u32)f2bf(acc0) | ((u32)f2bf(acc1) << 16);
    o.y = (u32)f2bf(acc2) | ((u32)f2bf(acc3) << 16);
    *reinterpret_cast<uint2*>(sb + (size_t)g * F_N + lane * 4) = o;
    if (lane == 0) Ag[g] = 1.f;
    return;
  }

  // ---- fallback (n > CAP, ~0.4% of graphs): drained global path ----
  float mx, inv, ee = 0.f;
  bool fast = (n <= 64);
  if (fast) {
    float z = (lane < n) ? lrelu(p + qreg) : -3.4e38f;
    mx = wave_max(z);
    ee = (lane < n) ? __expf(z - mx) : 0.f;
    inv = 1.f / wave_sum(ee);
    asm volatile("s_waitcnt vmcnt(0)" ::: "memory");  // xb stores -> visible
  } else {
    asm volatile("s_waitcnt vmcnt(0)" ::: "memory");  // q0/xb stores -> visible
    float mloc = -3.4e38f;
    for (int i = lane; i < n; i += 64) mloc = fmaxf(mloc, lrelu(p + q0[s + i]));
    mx = wave_max(mloc);
    float dloc = 0.f;
    for (int i = lane; i < n; i += 64) dloc += __expf(lrelu(p + q0[s + i]) - mx);
    inv = 1.f / wave_sum(dloc);
  }
  int half = lane >> 5;
  int cl = (lane & 31) * 8;
  float acc[8] = {0.f, 0.f, 0.f, 0.f, 0.f, 0.f, 0.f, 0.f};
  for (int i = 0; i < n; i += 2) {
    int r = i + half;
    float a;
    if (fast) {
      float ev = __shfl(ee, (r < 64 ? r : 63), 64);
      a = (r < n) ? ev * inv : 0.f;
    } else {
      a = (r < n) ? __expf(lrelu(p + q0[s + r]) - mx) * inv : 0.f;
    }
    int row = s + (r < n ? r : 0);
    uint2 x = *reinterpret_cast<const uint2*>(xb + (size_t)row * F_N + cl);
    acc[0] += a * e4m3f(x.x & 0xffu);
    acc[1] += a * e4m3f((x.x >> 8) & 0xffu);
    acc[2] += a * e4m3f((x.x >> 16) & 0xffu);
    acc[3] += a * e4m3f(x.x >> 24);
    acc[4] += a * e4m3f(x.y & 0xffu);
    acc[5] += a * e4m3f((x.y >> 8) & 0xffu);
    acc[6] += a * e4m3f((x.y >> 16) & 0xffu);
    acc[7] += a * e4m3f(x.y >> 24);
  }
#pragma unroll
  for (int k = 0; k < 8; ++k) acc[k] += __shfl_xor(acc[k], 32, 64);
  if (lane < 32) {
    uint4 o;
    o.x = (u32)f2bf(acc[0]) | ((u32)f2bf(acc[1]) << 16);
    o.y = (u32)f2bf(acc[2]) | ((u32)f2bf(acc[3]) << 16);
    o.z = (u32)f2bf(acc[4]) | ((u32)f2bf(acc[5]) << 16);
    o.w = (u32)f2bf(acc[6]) | ((u32)f2bf(acc[7]) << 16);
    *reinterpret_cast<uint4*>(sb + (size_t)g * F_N + cl) = o;
  }
  if (lane == 0) Ag[g] = 1.f;
}

// ---------------- attention t=1: wave-per-graph, fp8 xb (verified r10) ----------------
__global__ __launch_bounds__(256) void k_attn(const float* __restrict__ h,
                                              const u8* __restrict__ xb,
                                              const float* __restrict__ q,
                                              const int* __restrict__ off,
                                              const float* __restrict__ Wl,
                                              const float* __restrict__ bl, int t,
                                              u16* __restrict__ sb, float* __restrict__ Ag) {
  int g = blockIdx.x * 4 + (threadIdx.x >> 6);
  int lane = threadIdx.x & 63;
  if (g >= G_N) return;

  const float4 hv = *reinterpret_cast<const float4*>(h + (size_t)g * F_N + lane * 4);
  const float4 wv = *reinterpret_cast<const float4*>(Wl + t * 512 + lane * 4);
  float p = wave_sum(fmaxf(hv.x, 0.f) * wv.x + fmaxf(hv.y, 0.f) * wv.y +
                     fmaxf(hv.z, 0.f) * wv.z + fmaxf(hv.w, 0.f) * wv.w) + bl[t];

  int s = off[g], n = off[g + 1] - s;
  if (n == 0) {
    if (lane < 32) {
      uint4 z = {0u, 0u, 0u, 0u};
      *reinterpret_cast<uint4*>(sb + (size_t)g * F_N + lane * 8) = z;
    }
    if (lane == 0) Ag[g] = 0.f;
    return;
  }
  float mloc = -3.4e38f;
  for (int i = lane; i < n; i += 64) mloc = fmaxf(mloc, lrelu(p + q[s + i]));
  float mx = wave_max(mloc);
  float dloc = 0.f;
  for (int i = lane; i < n; i += 64) dloc += __expf(lrelu(p + q[s + i]) - mx);
  float inv = 1.f / wave_sum(dloc);

  int half = lane >> 5;
  int cl = (lane & 31) * 8;
  float acc[8] = {0.f, 0.f, 0.f, 0.f, 0.f, 0.f, 0.f, 0.f};
  for (int i = 0; i < n; i += 2) {
    int r = i + half;
    float a = 0.f;
    int row = s;
    if (r < n) {
      a = __expf(lrelu(p + q[s + r]) - mx) * inv;
      row = s + r;
    }
    uint2 x = *reinterpret_cast<const uint2*>(xb + (size_t)row * F_N + cl);
    acc[0] += a * e4m3f(x.x & 0xffu);
    acc[1] += a * e4m3f((x.x >> 8) & 0xffu);
    acc[2] += a * e4m3f((x.x >> 16) & 0xffu);
    acc[3] += a * e4m3f(x.x >> 24);
    acc[4] += a * e4m3f(x.y & 0xffu);
    acc[5] += a * e4m3f((x.y >> 8) & 0xffu);
    acc[6] += a * e4m3f((x.y >> 16) & 0xffu);
    acc[7] += a * e4m3f(x.y >> 24);
  }
#pragma unroll
  for (int k = 0; k < 8; ++k) acc[k] += __shfl_xor(acc[k], 32, 64);
  if (lane < 32) {
    uint4 o;
    o.x = (u32)f2bf(acc[0]) | ((u32)f2bf(acc[1]) << 16);
    o.y = (u32)f2bf(acc[2]) | ((u32)f2bf(acc[3]) << 16);
    o.z = (u32)f2bf(acc[4]) | ((u32)f2bf(acc[5]) << 16);
    o.w = (u32)f2bf(acc[6]) | ((u32)f2bf(acc[7]) << 16);
    *reinterpret_cast<uint4*>(sb + (size_t)g * F_N + cl) = o;
  }
  if (lane == 0) Ag[g] = 1.f;
}

// ---------------- bf16 MFMA GEMM (math verified r3-r10; XCD remap r6; gate-skip r9) ----------------
__global__ __launch_bounds__(256) void k_gemm(const u16* __restrict__ A, const u16* __restrict__ B,
                                              int K, float* __restrict__ dst,
                                              u16* __restrict__ x2out, const float* __restrict__ AgH,
                                              const float* __restrict__ b1, const float* __restrict__ b2,
                                              int mode, int writehb) {
  __shared__ __align__(16) u16 As[128 * 64];
  __shared__ __align__(16) u16 Bs[128 * 64];
  int tid = threadIdx.x, lane = tid & 63, w = tid >> 6;
  int gy = gridDim.y;
  int l = blockIdx.y * gridDim.x + blockIdx.x;
  int chunk = (gridDim.x * gy) >> 3;  // T divisible by 8
  int tau = (l & 7) * chunk + (l >> 3);
  int m0 = (tau / gy) * 128, n0 = (tau % gy) * 128;
  int nby = tau % gy;
  int wm = w >> 1, wn = w & 1;
  f32x4 zero = {0.f, 0.f, 0.f, 0.f};
  f32x4 acc[4][4];
#pragma unroll
  for (int i = 0; i < 4; ++i)
#pragma unroll
    for (int j = 0; j < 4; ++j) acc[i][j] = zero;

  int rowA = tid >> 3;
  int col8 = (tid & 7) * 8;
  for (int k0 = 0; k0 < K; k0 += 64) {
    __syncthreads();
#pragma unroll
    for (int c = 0; c < 4; ++c) {
      int r = c * 32 + rowA;
      const u16* gA = A + (size_t)(m0 + r) * K + k0 + col8;
      const u16* gB = B + (size_t)(n0 + r) * K + k0 + col8;
      char* lA = (char*)As + (c * 256 + w * 64) * 16;
      char* lB = (char*)Bs + (c * 256 + w * 64) * 16;
      load_lds16(gA, lA);
      load_lds16(gB, lB);
    }
    __syncthreads();
    int jskip = (mode == 2) ? ((k0 < 256) ? 3 : 2) : -1;
#pragma unroll
    for (int kk = 0; kk < 64; kk += 32) {
      bf16x8 af[4];
#pragma unroll
      for (int i = 0; i < 4; ++i)
        af[i] = *reinterpret_cast<const bf16x8*>(&As[(wm * 64 + i * 16 + (lane & 15)) * 64 + kk + (lane >> 4) * 8]);
#pragma unroll
      for (int j = 0; j < 4; ++j) {
        if (j == jskip) continue;
        bf16x8 bfr = *reinterpret_cast<const bf16x8*>(&Bs[(wn * 64 + j * 16 + (lane & 15)) * 64 + kk + (lane >> 4) * 8]);
#pragma unroll
        for (int i = 0; i < 4; ++i)
          acc[i][j] = __builtin_amdgcn_mfma_f32_16x16x32_bf16(af[i], bfr, acc[i][j], 0, 0, 0);
      }
    }
  }
  int crow0 = m0 + wm * 64 + (lane >> 4) * 4;
  if (mode == 1) {
    int ccol0 = n0 + wn * 64 + (lane & 15);
#pragma unroll
    for (int i = 0; i < 4; ++i)
#pragma unroll
      for (int j = 0; j < 4; ++j) {
        int col = ccol0 + j * 16;
#pragma unroll
        for (int r = 0; r < 4; ++r) {
          int row = crow0 + i * 16 + r;
          float v = acc[i][j][r] + AgH[row] * b1[col];
          v = v > 0.f ? v : (__expf(v) - 1.f);  // elu
          x2out[(size_t)row * 512 + col] = f2bf(v);
        }
      }
  } else {
    int qgrp = nby * 2 + wn;
    int c = qgrp * 16 + (lane & 15);
    float bi0 = b1[c] + b2[c];
    float bi1 = b1[256 + c] + b2[256 + c];
    float bi2 = b1[512 + c];
    float bi3 = b2[512 + c];
#pragma unroll
    for (int i = 0; i < 4; ++i)
#pragma unroll
      for (int r = 0; r < 4; ++r) {
        int grow = crow0 + i * 16 + r;
        if (grow >= G_N) continue;
        float ir = acc[i][0][r] + bi0;
        float iz = acc[i][1][r] + bi1;
        float nn = acc[i][2][r] + bi2;
        float hn = acc[i][3][r] + bi3;
        float rg = sigm(ir);
        float zg = sigm(iz);
        float h0 = AgH[(size_t)grow * F_N + c];
        float nv = tanh_fast(nn + rg * hn);
        float hN = (1.f - zg) * nv + zg * h0;
        dst[(size_t)grow * F_N + c] = hN;
        if (writehb) x2out[(size_t)grow * 512 + 256 + c] = f2bf(hN);
      }
  }
}

extern "C" void kernel_launch(void* const* d_in, const int* in_sizes, int n_in,
                              void* d_out, int out_size, void* d_ws, size_t ws_size,
                              hipStream_t stream) {
  const float* nf = (const float*)d_in[0];
  const int* seg = (const int*)d_in[1];
  const float* Wl = (const float*)d_in[2];
  const float* bl = (const float*)d_in[3];
  const float* Wp = (const float*)d_in[4];
  const float* bp = (const float*)d_in[5];
  const float* Wih = (const float*)d_in[6];
  const float* Whh = (const float*)d_in[7];
  const float* bih = (const float*)d_in[8];
  const float* bhh = (const float*)d_in[9];
  float* out = (float*)d_out;

  char* p = (char*)d_ws;
  auto alloc = [&](size_t bytes) {
    char* r = p;
    p += (bytes + 511) & ~(size_t)511;
    return r;
  };
  float* q0 = (float*)alloc((size_t)V_N * 4);
  float* q1 = (float*)alloc((size_t)V_N * 4);
  int* off = (int*)alloc((size_t)(G_N + 1) * 4);
  float* hbuf0 = (float*)alloc((size_t)GP_N * F_N * 4);
  float* hbuf1 = (float*)alloc((size_t)GP_N * F_N * 4);
  u16* sb = (u16*)alloc((size_t)GP_N * F_N * 2);
  float* Ag = (float*)alloc((size_t)GP_N * 4);
  u16* X2a = (u16*)alloc((size_t)GP_N * 512 * 2);
  u16* X2b = (u16*)alloc((size_t)GP_N * 512 * 2);
  u16* Wpb = (u16*)alloc((size_t)2 * F_N * F_N * 2);
  u16* W3 = (u16*)alloc((size_t)2 * 1024 * 512 * 2);
  u8* xb = (u8*)alloc((size_t)V_N * F_N);  // fp8 e4m3

  k_node_fused<<<CONVW_BLK + NODE_BLK, 256, 0, stream>>>(
      nf, seg, Wl, bl, xb, q0, q1, hbuf0, X2a, X2b, sb, Ag, off,
      Wp, Wih, Whh, Wpb, W3);

  // ---- t = 0 ----
  k_gemm<<<dim3(196, 2), 256, 0, stream>>>(sb, Wpb, 256,
                                           nullptr, X2a, Ag, bp, nullptr, 1, 0);
  k_gemm<<<dim3(196, 8), 256, 0, stream>>>(X2a, W3, 512,
                                           hbuf1, X2b, hbuf0, bih, bhh, 2, 1);
  // ---- t = 1 ----
  k_attn<<<G_N / 4, 256, 0, stream>>>(hbuf1, xb, q1, off, Wl, bl, 1, sb, Ag);
  k_gemm<<<dim3(196, 2), 256, 0, stream>>>(sb, Wpb + 65536, 256,
                                           nullptr, X2b, Ag, bp + 256, nullptr, 1, 0);
  k_gemm<<<dim3(196, 8), 256, 0, stream>>>(X2b, W3 + 524288, 512,
                                           out, nullptr, hbuf1, bih + 768, bhh + 768, 2, 0);
}

// Round 12
// 428.138 us; speedup vs baseline: 1.0461x; 1.0461x over previous
//
#include <hip/hip_runtime.h>
#include <cstdint>

typedef unsigned char u8;
typedef unsigned short u16;
typedef unsigned int u32;

#define V_N 500000
#define G_N 25000
#define F_N 256
#define GP_N 25088  // G padded to multiple of 128 for GEMM tiles

#define NODE_BLK (GP_N / 4)  // 6272 node blocks (4 waves/block, wave-per-graph)
#define CONVW_BLK 4608       // appended weight-conversion blocks

typedef __attribute__((ext_vector_type(8))) __bf16 bf16x8;
typedef __attribute__((ext_vector_type(4))) float f32x4;

__device__ __forceinline__ u16 f2bf(float f) {
  u32 u = __builtin_bit_cast(u32, f);
  u += 0x7fffu + ((u >> 16) & 1u);
  return (u16)(u >> 16);
}
__device__ __forceinline__ float bf2f(u16 s) {
  u32 u = ((u32)s) << 16;
  return __builtin_bit_cast(float, u);
}
// ---- fp8 e4m3fn encode/decode via bit tricks (no builtins; RNE rounding) ----
__device__ __forceinline__ u32 f2e4m3(float f) {
  u32 b = __builtin_bit_cast(u32, f * 0x1p-120f);
  u32 s = (b >> 24) & 0x80u;
  u32 ax = b & 0x7fffffffu;
  u32 r = (ax + 0x7FFFFu + ((ax >> 20) & 1u)) >> 20;
  r = r > 0x7Eu ? 0x7Eu : r;  // saturate below NaN encoding
  return s | r;
}
__device__ __forceinline__ float e4m3f(u32 byte) {
  u32 bits = ((byte & 0x80u) << 24) | ((byte & 0x7fu) << 20);
  return __builtin_bit_cast(float, bits) * 0x1p120f;
}
__device__ __forceinline__ float sigm(float x) { return 1.f / (1.f + __expf(-x)); }
__device__ __forceinline__ float tanh_fast(float x) {
  return 1.f - 2.f / (__expf(2.f * x) + 1.f);
}
__device__ __forceinline__ float lrelu(float z) { return z >= 0.f ? z : 0.01f * z; }

// ---- DPP wave reductions (verified r8) ----
template <int CTRL>
__device__ __forceinline__ float dpp_add_f(float v) {
  int t = __builtin_amdgcn_update_dpp(0, __builtin_bit_cast(int, v), CTRL, 0xF, 0xF, true);
  return v + __builtin_bit_cast(float, t);
}
template <int CTRL>
__device__ __forceinline__ float dpp_max_f(float v) {
  int t = __builtin_amdgcn_update_dpp(0, __builtin_bit_cast(int, v), CTRL, 0xF, 0xF, true);
  return fmaxf(v, __builtin_bit_cast(float, t));
}
__device__ __forceinline__ float wave_sum(float v) {
  v = dpp_add_f<0xB1>(v);
  v = dpp_add_f<0x4E>(v);
  v = dpp_add_f<0x141>(v);
  v = dpp_add_f<0x140>(v);
  v += __shfl_xor(v, 16, 64);
  v += __shfl_xor(v, 32, 64);
  return v;
}
__device__ __forceinline__ float wave_max(float v) {
  v = dpp_max_f<0xB1>(v);
  v = dpp_max_f<0x4E>(v);
  v = dpp_max_f<0x141>(v);
  v = dpp_max_f<0x140>(v);
  v = fmaxf(v, __shfl_xor(v, 16, 64));
  v = fmaxf(v, __shfl_xor(v, 32, 64));
  return v;
}

__device__ __forceinline__ void load_lds16(const void* g, void* l) {
  __builtin_amdgcn_global_load_lds(
      (const __attribute__((address_space(1))) void*)g,
      (__attribute__((address_space(3))) void*)l, 16, 0, 0);
}

// ---------------- fused node pass + t=0 attention + offsets + weight conv ----------------
__global__ __launch_bounds__(256) void k_node_fused(const float* __restrict__ nf,
                                                    const int* __restrict__ seg,
                                                    const float* __restrict__ Wl,
                                                    const float* __restrict__ bl,
                                                    u8* __restrict__ xb,
                                                    float* __restrict__ q0, float* __restrict__ q1,
                                                    float* __restrict__ hbuf0, u16* __restrict__ x2a,
                                                    u16* __restrict__ x2b,
                                                    u16* __restrict__ sb, float* __restrict__ Ag,
                                                    int* __restrict__ off,
                                                    const float* __restrict__ Wp,
                                                    const float* __restrict__ Wih,
                                                    const float* __restrict__ Whh,
                                                    u16* __restrict__ Wpb, u16* __restrict__ W3) {
  if (blockIdx.x >= NODE_BLK) {  // ---- weight conversion blocks (verified r3) ----
    int i = (blockIdx.x - NODE_BLK) * 256 + threadIdx.x;
    const int NP = 2 * F_N * F_N;  // 131072
    if (i < NP) {
      Wpb[i] = f2bf(Wp[i]);
      return;
    }
    int j = i - NP;  // < 2*1024*512
    int t = j >> 19;
    int r = j & 524287;
    int row = r >> 9;
    int k = r & 511;
    int q = row >> 6;
    int gate = (row >> 4) & 3;
    int c = q * 16 + (row & 15);
    const float* wi = Wih + t * 196608;
    const float* wh = Whh + t * 196608;
    float v;
    if (gate == 0) {
      v = (k < 256) ? wi[c * 256 + k] : wh[c * 256 + (k - 256)];
    } else if (gate == 1) {
      v = (k < 256) ? wi[(256 + c) * 256 + k] : wh[(256 + c) * 256 + (k - 256)];
    } else if (gate == 2) {
      v = (k < 256) ? wi[(512 + c) * 256 + k] : 0.f;
    } else {
      v = (k >= 256) ? wh[(512 + c) * 256 + (k - 256)] : 0.f;
    }
    W3[j] = f2bf(v);
    return;
  }

  int g = blockIdx.x * 4 + (threadIdx.x >> 6);
  int lane = threadIdx.x & 63;
  if (g >= G_N) {  // padding cleanup
    if (g == G_N && lane == 0) off[G_N] = V_N;
    if (g >= GP_N) return;
    float4 z4 = {0.f, 0.f, 0.f, 0.f};
    uint2 z2 = {0u, 0u};
    *reinterpret_cast<float4*>(hbuf0 + (size_t)g * F_N + lane * 4) = z4;
    *reinterpret_cast<uint2*>(x2a + (size_t)g * 512 + 256 + lane * 4) = z2;
    *reinterpret_cast<uint2*>(x2b + (size_t)g * 512 + 256 + lane * 4) = z2;
    *reinterpret_cast<uint2*>(sb + (size_t)g * F_N + lane * 4) = z2;
    if (lane == 0) Ag[g] = 0.f;
    return;
  }
  // ---- segment bounds via binary search (lane&1 -> target g / g+1) ----
  {
    int tgt = g + (lane & 1);
    int lo = 0, hi = V_N;
    while (lo < hi) {
      int mid = (lo + hi) >> 1;
      bool lt = seg[mid] < tgt;
      lo = lt ? mid + 1 : lo;
      hi = lt ? hi : mid;
    }
    int s_ = __shfl(lo, 0, 64);
    int e_ = __shfl(lo, 1, 64);
    if (lane == 0) off[g] = s_;  // for k_attn
    const float4 w0 = *reinterpret_cast<const float4*>(Wl + 256 + lane * 4);
    const float4 w1 = *reinterpret_cast<const float4*>(Wl + 768 + lane * 4);
    const float4 wh = *reinterpret_cast<const float4*>(Wl + lane * 4);  // t0 h-part
    int s = s_, e = e_;
    int n = e - s;
    float a0 = 0.f, a1 = 0.f, a2 = 0.f, a3 = 0.f;
    float qreg = 0.f;
    int v = s;
    for (; v + 2 <= e; v += 2) {
      const float4 xA = *reinterpret_cast<const float4*>(nf + (size_t)v * F_N + lane * 4);
      const float4 xB = *reinterpret_cast<const float4*>(nf + (size_t)(v + 1) * F_N + lane * 4);
      a0 += xA.x + xB.x; a1 += xA.y + xB.y; a2 += xA.z + xB.z; a3 += xA.w + xB.w;
      u32 pA = f2e4m3(xA.x) | (f2e4m3(xA.y) << 8) | (f2e4m3(xA.z) << 16) | (f2e4m3(xA.w) << 24);
      u32 pB = f2e4m3(xB.x) | (f2e4m3(xB.y) << 8) | (f2e4m3(xB.z) << 16) | (f2e4m3(xB.w) << 24);
      *reinterpret_cast<u32*>(xb + (size_t)v * F_N + lane * 4) = pA;
      *reinterpret_cast<u32*>(xb + (size_t)(v + 1) * F_N + lane * 4) = pB;
      float dA0 = wave_sum(xA.x * w0.x + xA.y * w0.y + xA.z * w0.z + xA.w * w0.w);
      float dA1 = wave_sum(xA.x * w1.x + xA.y * w1.y + xA.z * w1.z + xA.w * w1.w);
      float dB0 = wave_sum(xB.x * w0.x + xB.y * w0.y + xB.z * w0.z + xB.w * w0.w);
      float dB1 = wave_sum(xB.x * w1.x + xB.y * w1.y + xB.z * w1.z + xB.w * w1.w);
      if (lane == 0) {
        q0[v] = dA0; q1[v] = dA1;
        q0[v + 1] = dB0; q1[v + 1] = dB1;
      }
      int li = v - s;
      if (li == lane) qreg = dA0;
      if (li + 1 == lane) qreg = dB0;
    }
    if (v < e) {
      const float4 xA = *reinterpret_cast<const float4*>(nf + (size_t)v * F_N + lane * 4);
      a0 += xA.x; a1 += xA.y; a2 += xA.z; a3 += xA.w;
      u32 pA = f2e4m3(xA.x) | (f2e4m3(xA.y) << 8) | (f2e4m3(xA.z) << 16) | (f2e4m3(xA.w) << 24);
      *reinterpret_cast<u32*>(xb + (size_t)v * F_N + lane * 4) = pA;
      float dA0 = wave_sum(xA.x * w0.x + xA.y * w0.y + xA.z * w0.z + xA.w * w0.w);
      float dA1 = wave_sum(xA.x * w1.x + xA.y * w1.y + xA.z * w1.z + xA.w * w1.w);
      if (lane == 0) { q0[v] = dA0; q1[v] = dA1; }
      if (v - s == lane) qreg = dA0;
    }
    // h0 outputs
    float4 h4 = {a0, a1, a2, a3};
    *reinterpret_cast<float4*>(hbuf0 + (size_t)g * F_N + lane * 4) = h4;
    uint2 hs;
    hs.x = (u32)f2bf(a0) | ((u32)f2bf(a1) << 16);
    hs.y = (u32)f2bf(a2) | ((u32)f2bf(a3) << 16);
    *reinterpret_cast<uint2*>(x2a + (size_t)g * 512 + 256 + lane * 4) = hs;

    // ---- fused t=0 attention ----
    if (n == 0) {
      if (lane < 32) {
        uint4 z = {0u, 0u, 0u, 0u};
        *reinterpret_cast<uint4*>(sb + (size_t)g * F_N + lane * 8) = z;
      }
      if (lane == 0) Ag[g] = 0.f;
      return;
    }
    float p = wave_sum(fmaxf(a0, 0.f) * wh.x + fmaxf(a1, 0.f) * wh.y +
                       fmaxf(a2, 0.f) * wh.z + fmaxf(a3, 0.f) * wh.w) + bl[0];

    float mx, inv, ee = 0.f;
    bool fast = (n <= 64);
    if (fast) {
      float z = (lane < n) ? lrelu(p + qreg) : -3.4e38f;
      mx = wave_max(z);
      ee = (lane < n) ? __expf(z - mx) : 0.f;
      inv = 1.f / wave_sum(ee);
      asm volatile("s_waitcnt vmcnt(0)" ::: "memory");  // xb stores -> visible
    } else {
      asm volatile("s_waitcnt vmcnt(0)" ::: "memory");  // q0/xb stores -> visible
      float mloc = -3.4e38f;
      for (int i = lane; i < n; i += 64) mloc = fmaxf(mloc, lrelu(p + q0[s + i]));
      mx = wave_max(mloc);
      float dloc = 0.f;
      for (int i = lane; i < n; i += 64) dloc += __expf(lrelu(p + q0[s + i]) - mx);
      inv = 1.f / wave_sum(dloc);
    }

    int half = lane >> 5;
    int cl = (lane & 31) * 8;  // 8 fp8 cols per lane
    float acc[8] = {0.f, 0.f, 0.f, 0.f, 0.f, 0.f, 0.f, 0.f};
    for (int i = 0; i < n; i += 2) {
      int r = i + half;
      float a;
      if (fast) {
        float ev = __shfl(ee, (r < 64 ? r : 63), 64);
        a = (r < n) ? ev * inv : 0.f;
      } else {
        a = (r < n) ? __expf(lrelu(p + q0[s + r]) - mx) * inv : 0.f;
      }
      int row = s + (r < n ? r : 0);
      uint2 x = *reinterpret_cast<const uint2*>(xb + (size_t)row * F_N + cl);
      acc[0] += a * e4m3f(x.x & 0xffu);
      acc[1] += a * e4m3f((x.x >> 8) & 0xffu);
      acc[2] += a * e4m3f((x.x >> 16) & 0xffu);
      acc[3] += a * e4m3f(x.x >> 24);
      acc[4] += a * e4m3f(x.y & 0xffu);
      acc[5] += a * e4m3f((x.y >> 8) & 0xffu);
      acc[6] += a * e4m3f((x.y >> 16) & 0xffu);
      acc[7] += a * e4m3f(x.y >> 24);
    }
#pragma unroll
    for (int k = 0; k < 8; ++k) acc[k] += __shfl_xor(acc[k], 32, 64);
    if (lane < 32) {
      uint4 o;
      o.x = (u32)f2bf(acc[0]) | ((u32)f2bf(acc[1]) << 16);
      o.y = (u32)f2bf(acc[2]) | ((u32)f2bf(acc[3]) << 16);
      o.z = (u32)f2bf(acc[4]) | ((u32)f2bf(acc[5]) << 16);
      o.w = (u32)f2bf(acc[6]) | ((u32)f2bf(acc[7]) << 16);
      *reinterpret_cast<uint4*>(sb + (size_t)g * F_N + cl) = o;
    }
    if (lane == 0) Ag[g] = 1.f;
  }
}

// ---------------- attention t=1: wave-per-graph, fp8 xb (verified r10) ----------------
__global__ __launch_bounds__(256) void k_attn(const float* __restrict__ h,
                                              const u8* __restrict__ xb,
                                              const float* __restrict__ q,
                                              const int* __restrict__ off,
                                              const float* __restrict__ Wl,
                                              const float* __restrict__ bl, int t,
                                              u16* __restrict__ sb, float* __restrict__ Ag) {
  int g = blockIdx.x * 4 + (threadIdx.x >> 6);
  int lane = threadIdx.x & 63;
  if (g >= G_N) return;

  const float4 hv = *reinterpret_cast<const float4*>(h + (size_t)g * F_N + lane * 4);
  const float4 wv = *reinterpret_cast<const float4*>(Wl + t * 512 + lane * 4);
  float p = wave_sum(fmaxf(hv.x, 0.f) * wv.x + fmaxf(hv.y, 0.f) * wv.y +
                     fmaxf(hv.z, 0.f) * wv.z + fmaxf(hv.w, 0.f) * wv.w) + bl[t];

  int s = off[g], n = off[g + 1] - s;
  if (n == 0) {
    if (lane < 32) {
      uint4 z = {0u, 0u, 0u, 0u};
      *reinterpret_cast<uint4*>(sb + (size_t)g * F_N + lane * 8) = z;
    }
    if (lane == 0) Ag[g] = 0.f;
    return;
  }
  float mloc = -3.4e38f;
  for (int i = lane; i < n; i += 64) mloc = fmaxf(mloc, lrelu(p + q[s + i]));
  float mx = wave_max(mloc);
  float dloc = 0.f;
  for (int i = lane; i < n; i += 64) dloc += __expf(lrelu(p + q[s + i]) - mx);
  float inv = 1.f / wave_sum(dloc);

  int half = lane >> 5;
  int cl = (lane & 31) * 8;
  float acc[8] = {0.f, 0.f, 0.f, 0.f, 0.f, 0.f, 0.f, 0.f};
  for (int i = 0; i < n; i += 2) {
    int r = i + half;
    float a = 0.f;
    int row = s;
    if (r < n) {
      a = __expf(lrelu(p + q[s + r]) - mx) * inv;
      row = s + r;
    }
    uint2 x = *reinterpret_cast<const uint2*>(xb + (size_t)row * F_N + cl);
    acc[0] += a * e4m3f(x.x & 0xffu);
    acc[1] += a * e4m3f((x.x >> 8) & 0xffu);
    acc[2] += a * e4m3f((x.x >> 16) & 0xffu);
    acc[3] += a * e4m3f(x.x >> 24);
    acc[4] += a * e4m3f(x.y & 0xffu);
    acc[5] += a * e4m3f((x.y >> 8) & 0xffu);
    acc[6] += a * e4m3f((x.y >> 16) & 0xffu);
    acc[7] += a * e4m3f(x.y >> 24);
  }
#pragma unroll
  for (int k = 0; k < 8; ++k) acc[k] += __shfl_xor(acc[k], 32, 64);
  if (lane < 32) {
    uint4 o;
    o.x = (u32)f2bf(acc[0]) | ((u32)f2bf(acc[1]) << 16);
    o.y = (u32)f2bf(acc[2]) | ((u32)f2bf(acc[3]) << 16);
    o.z = (u32)f2bf(acc[4]) | ((u32)f2bf(acc[5]) << 16);
    o.w = (u32)f2bf(acc[6]) | ((u32)f2bf(acc[7]) << 16);
    *reinterpret_cast<uint4*>(sb + (size_t)g * F_N + cl) = o;
  }
  if (lane == 0) Ag[g] = 1.f;
}

// ---------------- bf16 MFMA GEMM (math verified r3-r10; XCD remap r6; gate-skip r9) ----------------
__global__ __launch_bounds__(256) void k_gemm(const u16* __restrict__ A, const u16* __restrict__ B,
                                              int K, float* __restrict__ dst,
                                              u16* __restrict__ x2out, const float* __restrict__ AgH,
                                              const float* __restrict__ b1, const float* __restrict__ b2,
                                              int mode, int writehb) {
  __shared__ __align__(16) u16 As[128 * 64];
  __shared__ __align__(16) u16 Bs[128 * 64];
  int tid = threadIdx.x, lane = tid & 63, w = tid >> 6;
  int gy = gridDim.y;
  int l = blockIdx.y * gridDim.x + blockIdx.x;
  int chunk = (gridDim.x * gy) >> 3;  // T divisible by 8
  int tau = (l & 7) * chunk + (l >> 3);
  int m0 = (tau / gy) * 128, n0 = (tau % gy) * 128;
  int nby = tau % gy;
  int wm = w >> 1, wn = w & 1;
  f32x4 zero = {0.f, 0.f, 0.f, 0.f};
  f32x4 acc[4][4];
#pragma unroll
  for (int i = 0; i < 4; ++i)
#pragma unroll
    for (int j = 0; j < 4; ++j) acc[i][j] = zero;

  int rowA = tid >> 3;
  int col8 = (tid & 7) * 8;
  for (int k0 = 0; k0 < K; k0 += 64) {
    __syncthreads();
#pragma unroll
    for (int c = 0; c < 4; ++c) {
      int r = c * 32 + rowA;
      const u16* gA = A + (size_t)(m0 + r) * K + k0 + col8;
      const u16* gB = B + (size_t)(n0 + r) * K + k0 + col8;
      char* lA = (char*)As + (c * 256 + w * 64) * 16;
      char* lB = (char*)Bs + (c * 256 + w * 64) * 16;
      load_lds16(gA, lA);
      load_lds16(gB, lB);
    }
    __syncthreads();
    int jskip = (mode == 2) ? ((k0 < 256) ? 3 : 2) : -1;
#pragma unroll
    for (int kk = 0; kk < 64; kk += 32) {
      bf16x8 af[4];
#pragma unroll
      for (int i = 0; i < 4; ++i)
        af[i] = *reinterpret_cast<const bf16x8*>(&As[(wm * 64 + i * 16 + (lane & 15)) * 64 + kk + (lane >> 4) * 8]);
#pragma unroll
      for (int j = 0; j < 4; ++j) {
        if (j == jskip) continue;
        bf16x8 bfr = *reinterpret_cast<const bf16x8*>(&Bs[(wn * 64 + j * 16 + (lane & 15)) * 64 + kk + (lane >> 4) * 8]);
#pragma unroll
        for (int i = 0; i < 4; ++i)
          acc[i][j] = __builtin_amdgcn_mfma_f32_16x16x32_bf16(af[i], bfr, acc[i][j], 0, 0, 0);
      }
    }
  }
  int crow0 = m0 + wm * 64 + (lane >> 4) * 4;
  if (mode == 1) {
    int ccol0 = n0 + wn * 64 + (lane & 15);
#pragma unroll
    for (int i = 0; i < 4; ++i)
#pragma unroll
      for (int j = 0; j < 4; ++j) {
        int col = ccol0 + j * 16;
#pragma unroll
        for (int r = 0; r < 4; ++r) {
          int row = crow0 + i * 16 + r;
          float v = acc[i][j][r] + AgH[row] * b1[col];
          v = v > 0.f ? v : (__expf(v) - 1.f);  // elu
          x2out[(size_t)row * 512 + col] = f2bf(v);
        }
      }
  } else {
    int qgrp = nby * 2 + wn;
    int c = qgrp * 16 + (lane & 15);
    float bi0 = b1[c] + b2[c];
    float bi1 = b1[256 + c] + b2[256 + c];
    float bi2 = b1[512 + c];
    float bi3 = b2[512 + c];
#pragma unroll
    for (int i = 0; i < 4; ++i)
#pragma unroll
      for (int r = 0; r < 4; ++r) {
        int grow = crow0 + i * 16 + r;
        if (grow >= G_N) continue;
        float ir = acc[i][0][r] + bi0;
        float iz = acc[i][1][r] + bi1;
        float nn = acc[i][2][r] + bi2;
        float hn = acc[i][3][r] + bi3;
        float rg = sigm(ir);
        float zg = sigm(iz);
        float h0 = AgH[(size_t)grow * F_N + c];
        float nv = tanh_fast(nn + rg * hn);
        float hN = (1.f - zg) * nv + zg * h0;
        dst[(size_t)grow * F_N + c] = hN;
        if (writehb) x2out[(size_t)grow * 512 + 256 + c] = f2bf(hN);
      }
  }
}

extern "C" void kernel_launch(void* const* d_in, const int* in_sizes, int n_in,
                              void* d_out, int out_size, void* d_ws, size_t ws_size,
                              hipStream_t stream) {
  const float* nf = (const float*)d_in[0];
  const int* seg = (const int*)d_in[1];
  const float* Wl = (const float*)d_in[2];
  const float* bl = (const float*)d_in[3];
  const float* Wp = (const float*)d_in[4];
  const float* bp = (const float*)d_in[5];
  const float* Wih = (const float*)d_in[6];
  const float* Whh = (const float*)d_in[7];
  const float* bih = (const float*)d_in[8];
  const float* bhh = (const float*)d_in[9];
  float* out = (float*)d_out;

  char* p = (char*)d_ws;
  auto alloc = [&](size_t bytes) {
    char* r = p;
    p += (bytes + 511) & ~(size_t)511;
    return r;
  };
  float* q0 = (float*)alloc((size_t)V_N * 4);
  float* q1 = (float*)alloc((size_t)V_N * 4);
  int* off = (int*)alloc((size_t)(G_N + 1) * 4);
  float* hbuf0 = (float*)alloc((size_t)GP_N * F_N * 4);
  float* hbuf1 = (float*)alloc((size_t)GP_N * F_N * 4);
  u16* sb = (u16*)alloc((size_t)GP_N * F_N * 2);
  float* Ag = (float*)alloc((size_t)GP_N * 4);
  u16* X2a = (u16*)alloc((size_t)GP_N * 512 * 2);
  u16* X2b = (u16*)alloc((size_t)GP_N * 512 * 2);
  u16* Wpb = (u16*)alloc((size_t)2 * F_N * F_N * 2);
  u16* W3 = (u16*)alloc((size_t)2 * 1024 * 512 * 2);
  u8* xb = (u8*)alloc((size_t)V_N * F_N);  // fp8 e4m3

  k_node_fused<<<NODE_BLK + CONVW_BLK, 256, 0, stream>>>(
      nf, seg, Wl, bl, xb, q0, q1, hbuf0, X2a, X2b, sb, Ag, off,
      Wp, Wih, Whh, Wpb, W3);

  // ---- t = 0 ----
  k_gemm<<<dim3(196, 2), 256, 0, stream>>>(sb, Wpb, 256,
                                           nullptr, X2a, Ag, bp, nullptr, 1, 0);
  k_gemm<<<dim3(196, 8), 256, 0, stream>>>(X2a, W3, 512,
                                           hbuf1, X2b, hbuf0, bih, bhh, 2, 1);
  // ---- t = 1 ----
  k_attn<<<G_N / 4, 256, 0, stream>>>(hbuf1, xb, q1, off, Wl, bl, 1, sb, Ag);
  k_gemm<<<dim3(196, 2), 256, 0, stream>>>(sb, Wpb + 65536, 256,
                                           nullptr, X2b, Ag, bp + 256, nullptr, 1, 0);
  k_gemm<<<dim3(196, 8), 256, 0, stream>>>(X2b, W3 + 524288, 512,
                                           out, nullptr, hbuf1, bih + 768, bhh + 768, 2, 0);
}